// Round 2
// baseline (385.955 us; speedup 1.0000x reference)
//
#include <hip/hip_runtime.h>
#include <math.h>

// Problem constants (from reference)
#define BB 4
#define NN 1024
#define EE 1024
#define HH 16
#define DD 64
#define MAXLEN 512
#define EPS 1e-5f

typedef __attribute__((ext_vector_type(8))) __bf16 bf16x8;
typedef __attribute__((ext_vector_type(4))) float floatx4;
typedef __attribute__((ext_vector_type(8))) unsigned short ushort8;

__device__ __forceinline__ unsigned short f2bf(float f) {
    unsigned u = __float_as_uint(f);
    u += 0x7fffu + ((u >> 16) & 1u);   // RNE
    return (unsigned short)(u >> 16);
}
__device__ __forceinline__ float bf2f(unsigned short h) {
    return __uint_as_float(((unsigned)h) << 16);
}

// ---------------------------------------------------------------------------
// fp32 -> bf16 conversion (vectorized by 4)
// ---------------------------------------------------------------------------
__global__ __launch_bounds__(256) void f2bf_kernel(const float* __restrict__ in,
                                                   unsigned short* __restrict__ out,
                                                   int n4) {
    int i = blockIdx.x * 256 + threadIdx.x;
    if (i < n4) {
        float4 v = ((const float4*)in)[i];
        ushort4 o;
        o.x = f2bf(v.x); o.y = f2bf(v.y); o.z = f2bf(v.z); o.w = f2bf(v.w);
        ((ushort4*)out)[i] = o;
    }
}

// ---------------------------------------------------------------------------
// LayerNorm: one block (256 threads) per row of E=1024; bf16 output.
// ---------------------------------------------------------------------------
__global__ __launch_bounds__(256) void ln_kernel(const float* __restrict__ x,
                                                 const float* __restrict__ g,
                                                 const float* __restrict__ b,
                                                 unsigned short* __restrict__ out) {
    const int row = blockIdx.x;
    const float* xr = x + (size_t)row * EE;
    float s = 0.f, s2 = 0.f;
    for (int j = threadIdx.x; j < EE; j += 256) {
        float v = xr[j];
        s += v; s2 += v * v;
    }
    for (int off = 32; off > 0; off >>= 1) {
        s  += __shfl_xor(s, off);
        s2 += __shfl_xor(s2, off);
    }
    __shared__ float red[8];
    const int wave = threadIdx.x >> 6, lane = threadIdx.x & 63;
    if (lane == 0) { red[wave] = s; red[4 + wave] = s2; }
    __syncthreads();
    s  = red[0] + red[1] + red[2] + red[3];
    s2 = red[4] + red[5] + red[6] + red[7];
    const float mu  = s * (1.0f / EE);
    const float var = s2 * (1.0f / EE) - mu * mu;
    const float inv = rsqrtf(var + EPS);
    unsigned short* orow = out + (size_t)row * EE;
    for (int j = threadIdx.x; j < EE; j += 256) {
        orow[j] = f2bf((xr[j] - mu) * inv * g[j] + b[j]);
    }
}

// ---------------------------------------------------------------------------
// OLD bf16 MFMA GEMM (2-barrier structure) — retained for out-proj only.
// C[M,Nc] = A[M,K] @ W[Nc,K]^T + bias (+res) (relu)
// ---------------------------------------------------------------------------
template <int TN, int NSUB, bool RELU, bool HAS_RES, bool OUT_BF16>
__global__ __launch_bounds__(256) void gemm_bf16_kernel(
    const unsigned short* __restrict__ A,
    const unsigned short* __restrict__ W,
    const float* __restrict__ bias,
    const float* res, void* Cout, int M, int Nc, int K) {
    constexpr int WN = TN / 2;       // wave N extent: 64 or 32
    constexpr int NJ = WN / 16;      // N frags per wave: 4 or 2
    constexpr int BI = TN / 64;      // B staging issues per wave per subtile
    __shared__ unsigned short As[NSUB][128 * 32];
    __shared__ unsigned short Bs[NSUB][TN * 32];

    const int tid  = threadIdx.x;
    const int lane = tid & 63;
    const int wv   = tid >> 6;
    const int row0 = blockIdx.y * 128;
    const int col0 = blockIdx.x * TN;
    const int waveM = (wv & 1) * 64;
    const int waveN = (wv >> 1) * WN;

    floatx4 acc[4][NJ];
#pragma unroll
    for (int i = 0; i < 4; ++i)
#pragma unroll
        for (int j = 0; j < NJ; ++j) acc[i][j] = (floatx4){0.f, 0.f, 0.f, 0.f};

    const int lrow = lane >> 2;        // staging: lane covers row lrow, 8 elems
    const int lk8  = (lane & 3) * 8;
    const int frow = lane & 15;        // fragment row
    const int kc8  = (lane >> 4) * 8;  // fragment k offset

    for (int k0 = 0; k0 < K; k0 += 32 * NSUB) {
#pragma unroll
        for (int s = 0; s < NSUB; ++s) {
            const int kk = k0 + s * 32;
#pragma unroll
            for (int q = 0; q < 2; ++q) {
                const int r = wv * 32 + q * 16;
                const unsigned short* ga = A + (size_t)(row0 + r + lrow) * K + kk + lk8;
                __builtin_amdgcn_global_load_lds(
                    (const __attribute__((address_space(1))) unsigned int*)ga,
                    (__attribute__((address_space(3))) unsigned int*)&As[s][r * 32], 16, 0, 0);
            }
#pragma unroll
            for (int q = 0; q < BI; ++q) {
                const int r = wv * (16 * BI) + q * 16;
                const unsigned short* gb = W + (size_t)(col0 + r + lrow) * K + kk + lk8;
                __builtin_amdgcn_global_load_lds(
                    (const __attribute__((address_space(1))) unsigned int*)gb,
                    (__attribute__((address_space(3))) unsigned int*)&Bs[s][r * 32], 16, 0, 0);
            }
        }
        __syncthreads();   // all sub-tiles resident

#pragma unroll
        for (int s = 0; s < NSUB; ++s) {
            bf16x8 af[4], bfr[NJ];
#pragma unroll
            for (int t = 0; t < 4; ++t)
                af[t] = *(const bf16x8*)&As[s][(waveM + t * 16 + frow) * 32 + kc8];
#pragma unroll
            for (int t = 0; t < NJ; ++t)
                bfr[t] = *(const bf16x8*)&Bs[s][(waveN + t * 16 + frow) * 32 + kc8];
#pragma unroll
            for (int i = 0; i < 4; ++i)
#pragma unroll
                for (int j = 0; j < NJ; ++j)
                    acc[i][j] = __builtin_amdgcn_mfma_f32_16x16x32_bf16(
                        af[i], bfr[j], acc[i][j], 0, 0, 0);
        }
        __syncthreads();   // tiles free for overwrite
    }

    float* Cf = (float*)Cout;
    unsigned short* Cb = (unsigned short*)Cout;
    const int crow = (lane >> 4) * 4;
    const int ccol = lane & 15;
#pragma unroll
    for (int j = 0; j < NJ; ++j) {
        const int n = col0 + waveN + j * 16 + ccol;
        const float bv = bias[n];
#pragma unroll
        for (int i = 0; i < 4; ++i) {
#pragma unroll
            for (int r = 0; r < 4; ++r) {
                const int m = row0 + waveM + i * 16 + crow + r;
                float v = acc[i][j][r] + bv;
                if (HAS_RES) v += res[(size_t)m * Nc + n];
                if (RELU) v = fmaxf(v, 0.f);
                if (OUT_BF16) Cb[(size_t)m * Nc + n] = f2bf(v);
                else          Cf[(size_t)m * Nc + n] = v;
            }
        }
    }
}

// ---------------------------------------------------------------------------
// NEW: 256x256 MFMA GEMM, 8 waves (512 thr), 4-deep BK=32 ring buffer in LDS
// (128 KB), counted-vmcnt software pipeline (T3+T4) + setprio (T5).
// Schedule per K-tile t (2 phases, 2 raw barriers each):
//   ph0: issue stage A-halves of tile t+3 -> buf[(t+3)&3]  (2 vm units)
//        ds_read af[8] + bf[0..1] from buf[t&3]
//        s_barrier; lgkmcnt(0); 16 MFMA (n-cols 0..31)
//        s_barrier
//   ph1: issue stage B-halves of tile t+3                   (2 vm units)
//        ds_read bf[0..1] (n-cols 32..63)
//        counted s_waitcnt vmcnt(8)  -> tile t+1 resident (t+2,t+3 in flight)
//        s_barrier; lgkmcnt(0); 16 MFMA (n-cols 32..63)
//        s_barrier
// Residency ledger (steady state, per wave, 4 loads/tile): at ph1 wait point
// 12 outstanding (t+1,t+2,t+3) -> vmcnt(8) drains tile t+1; barrier makes it
// block-wide. WAR on buf[(t+3)&3]==buf[(t-1)&3] sealed by two barriers.
// sched_barrier(0) after EVERY s_barrier: raw s_barrier is not a compiler
// memory fence — without the pin, LLVM may hoist tile-t ds_reads above the
// barrier that guarantees OTHER waves' tile-t global_load_lds completed.
// VARIANT: 0 = bias + bf16 out; 1 = bias + relu + bf16 out;
//          2 = split-K: f32 atomicAdd into Cout (+bias only on blockIdx.z==0)
// Requires M%256==0, Nc%256==0, Kslice%32==0, Kslice/32 >= 4.
// ---------------------------------------------------------------------------
template <int VARIANT>
__global__ __launch_bounds__(512, 2) void gemm256_kernel(
    const unsigned short* __restrict__ A,
    const unsigned short* __restrict__ W,
    const float* __restrict__ bias,
    void* __restrict__ Cout,
    int Nc, int K, int Kslice) {
    // ring buffer: per buf, A tile [256][32] at [0..8191], B tile at [8192..16383]
    __shared__ unsigned short smem[4][16384];   // 128 KB

    const int tid  = threadIdx.x;
    const int lane = tid & 63;
    const int wv   = tid >> 6;          // 0..7
    const int wm   = wv >> 2;           // 0..1 (M half)
    const int wn   = wv & 3;            // 0..3 (N quarter)
    const int row0 = blockIdx.y * 256;
    const int col0 = blockIdx.x * 256;
    const int kbase = blockIdx.z * Kslice;
    const int NT   = Kslice >> 5;       // K-tiles of 32

    // staging source coords (lane covers row lane>>2, 8 elems at (lane&3)*8)
    const int srow = lane >> 2;
    const int sk8  = (lane & 3) * 8;
    const unsigned short* Ag = A + (size_t)(row0 + srow) * K + kbase + sk8;
    const unsigned short* Wg = W + (size_t)(col0 + srow) * K + kbase + sk8;

    auto stageA = [&](int t, int h) {   // h: rows [h*128, +128)
        const int r = h * 128 + wv * 16;   // wave-uniform LDS base row
        __builtin_amdgcn_global_load_lds(
            (const __attribute__((address_space(1))) unsigned int*)(Ag + (size_t)r * K + t * 32),
            (__attribute__((address_space(3))) unsigned int*)&smem[t & 3][r * 32], 16, 0, 0);
    };
    auto stageB = [&](int t, int h) {
        const int r = h * 128 + wv * 16;
        __builtin_amdgcn_global_load_lds(
            (const __attribute__((address_space(1))) unsigned int*)(Wg + (size_t)r * K + t * 32),
            (__attribute__((address_space(3))) unsigned int*)&smem[t & 3][8192 + r * 32], 16, 0, 0);
    };

    floatx4 acc[8][4];
#pragma unroll
    for (int m = 0; m < 8; ++m)
#pragma unroll
        for (int n = 0; n < 4; ++n) acc[m][n] = (floatx4){0.f, 0.f, 0.f, 0.f};

    const int frow = lane & 15;         // fragment row
    const int q8   = (lane >> 4) * 8;   // fragment k offset (elems)

    // ---- prologue: stage tiles 0,1,2 (12 vm units); wait tile 0 (leave 8) ----
#pragma unroll
    for (int pt = 0; pt < 3; ++pt) {
        stageA(pt, 0); stageA(pt, 1); stageB(pt, 0); stageB(pt, 1);
    }
    asm volatile("s_waitcnt vmcnt(8)" ::: "memory");
    __builtin_amdgcn_s_barrier();
    __builtin_amdgcn_sched_barrier(0);

    for (int t = 0; t < NT; ++t) {
        const unsigned short* Ab = &smem[t & 3][0];
        const unsigned short* Bb = &smem[t & 3][8192];
        bf16x8 af[8], bfr[2];

        // ---------------- phase 0 ----------------
        if (t + 3 < NT) { stageA(t + 3, 0); stageA(t + 3, 1); }
#pragma unroll
        for (int m = 0; m < 8; ++m)
            af[m] = *(const bf16x8*)(Ab + (wm * 128 + m * 16 + frow) * 32 + q8);
#pragma unroll
        for (int j = 0; j < 2; ++j)
            bfr[j] = *(const bf16x8*)(Bb + (wn * 64 + j * 16 + frow) * 32 + q8);
        __builtin_amdgcn_s_barrier();
        asm volatile("s_waitcnt lgkmcnt(0)" ::: "memory");
        __builtin_amdgcn_sched_barrier(0);
        __builtin_amdgcn_s_setprio(1);
#pragma unroll
        for (int m = 0; m < 8; ++m) {
            acc[m][0] = __builtin_amdgcn_mfma_f32_16x16x32_bf16(af[m], bfr[0], acc[m][0], 0, 0, 0);
            acc[m][1] = __builtin_amdgcn_mfma_f32_16x16x32_bf16(af[m], bfr[1], acc[m][1], 0, 0, 0);
        }
        __builtin_amdgcn_s_setprio(0);
        __builtin_amdgcn_sched_barrier(0);
        __builtin_amdgcn_s_barrier();
        __builtin_amdgcn_sched_barrier(0);

        // ---------------- phase 1 ----------------
        if (t + 3 < NT) { stageB(t + 3, 0); stageB(t + 3, 1); }
#pragma unroll
        for (int j = 0; j < 2; ++j)
            bfr[j] = *(const bf16x8*)(Bb + (wn * 64 + 32 + j * 16 + frow) * 32 + q8);
        // counted wait: ensure tile t+1 resident; keep t+2,t+3 in flight
        if (t <= NT - 4)      { asm volatile("s_waitcnt vmcnt(8)" ::: "memory"); }
        else if (t == NT - 3) { asm volatile("s_waitcnt vmcnt(4)" ::: "memory"); }
        else if (t == NT - 2) { asm volatile("s_waitcnt vmcnt(0)" ::: "memory"); }
        __builtin_amdgcn_s_barrier();
        asm volatile("s_waitcnt lgkmcnt(0)" ::: "memory");
        __builtin_amdgcn_sched_barrier(0);
        __builtin_amdgcn_s_setprio(1);
#pragma unroll
        for (int m = 0; m < 8; ++m) {
            acc[m][2] = __builtin_amdgcn_mfma_f32_16x16x32_bf16(af[m], bfr[0], acc[m][2], 0, 0, 0);
            acc[m][3] = __builtin_amdgcn_mfma_f32_16x16x32_bf16(af[m], bfr[1], acc[m][3], 0, 0, 0);
        }
        __builtin_amdgcn_s_setprio(0);
        __builtin_amdgcn_sched_barrier(0);
        __builtin_amdgcn_s_barrier();
        __builtin_amdgcn_sched_barrier(0);
    }

    // ---------------- epilogue ----------------
    const int crow = (lane >> 4) * 4;
    const int ccol = lane & 15;
    if (VARIANT == 2) {
        float* Cf = (float*)Cout;
        const bool addb = (blockIdx.z == 0);
#pragma unroll
        for (int n = 0; n < 4; ++n) {
            const int nn = col0 + wn * 64 + n * 16 + ccol;
            const float bv = addb ? bias[nn] : 0.f;
#pragma unroll
            for (int m = 0; m < 8; ++m) {
#pragma unroll
                for (int r = 0; r < 4; ++r) {
                    const int mm = row0 + wm * 128 + m * 16 + crow + r;
                    atomicAdd(&Cf[(size_t)mm * Nc + nn], acc[m][n][r] + bv);
                }
            }
        }
    } else {
        unsigned short* Cb = (unsigned short*)Cout;
#pragma unroll
        for (int n = 0; n < 4; ++n) {
            const int nn = col0 + wn * 64 + n * 16 + ccol;
            const float bv = bias[nn];
#pragma unroll
            for (int m = 0; m < 8; ++m) {
#pragma unroll
                for (int r = 0; r < 4; ++r) {
                    const int mm = row0 + wm * 128 + m * 16 + crow + r;
                    float v = acc[m][n][r] + bv;
                    if (VARIANT == 1) v = fmaxf(v, 0.f);
                    Cb[(size_t)mm * Nc + nn] = f2bf(v);
                }
            }
        }
    }
}

// ---------------------------------------------------------------------------
// Flash-style MFMA attention. rel_bias(i,j) finite only for 0 <= i-j < 512
// (causal sliding window). One block = 64 Q rows for (b,h); 4 waves, each
// owns 16 Q rows. QK^T and PV via mfma_f32_16x16x32_bf16; online softmax.
// ---------------------------------------------------------------------------
__global__ __launch_bounds__(256) void attn_mfma_kernel(
    const unsigned short* __restrict__ qkv,
    const float* __restrict__ rel_pos,
    unsigned short* __restrict__ o) {
    __shared__ unsigned short K_s[2][64][32];     // 8 KB
    __shared__ unsigned short V_s[64][72];        // 9 KB  [d][key]
    __shared__ unsigned short P_s[4][2][16][32];  // 8 KB  per-wave
    __shared__ float rel_s[MAXLEN];               // 2 KB

    const int qt = blockIdx.x, h = blockIdx.y, b = blockIdx.z;
    const int q0 = qt * 64;
    const int tid  = threadIdx.x;
    const int lane = tid & 63;
    const int w    = tid >> 6;
    const int quad = lane >> 4;
    const int c15  = lane & 15;

    rel_s[tid]       = rel_pos[h * MAXLEN + tid];
    rel_s[tid + 256] = rel_pos[h * MAXLEN + tid + 256];

    const size_t rowstride = 3 * EE;
    const size_t base_q = (size_t)(b * NN) * rowstride + h * DD;
    const size_t base_k = base_q + EE;
    const size_t base_v = base_q + 2 * EE;

    bf16x8 aq[2];
    {
        const unsigned short* qrow =
            qkv + base_q + (size_t)(q0 + w * 16 + c15) * rowstride + quad * 8;
        aq[0] = *(const bf16x8*)(qrow);
        aq[1] = *(const bf16x8*)(qrow + 32);
    }

    floatx4 Oacc[4];
#pragma unroll
    for (int j = 0; j < 4; ++j) Oacc[j] = (floatx4){0.f, 0.f, 0.f, 0.f};
    float m_r[4], l_r[4];
#pragma unroll
    for (int r = 0; r < 4; ++r) { m_r[r] = -1e30f; l_r[r] = 0.f; }

    const int jlo = max(0, q0 - (MAXLEN - 1));
    const int c0 = jlo >> 6;
    const int c1 = (q0 + 63) >> 6;

    for (int cc = c0; cc <= c1; ++cc) {
        const int jb0 = cc << 6;
        __syncthreads();

        {
            const int krow = w * 16 + (lane >> 2);
            const int dofs = (lane & 3) * 8;
            const unsigned short* gk =
                qkv + base_k + (size_t)(jb0 + krow) * rowstride + dofs;
            __builtin_amdgcn_global_load_lds(
                (const __attribute__((address_space(1))) unsigned int*)gk,
                (__attribute__((address_space(3))) unsigned int*)&K_s[0][w * 16][0],
                16, 0, 0);
            __builtin_amdgcn_global_load_lds(
                (const __attribute__((address_space(1))) unsigned int*)(gk + 32),
                (__attribute__((address_space(3))) unsigned int*)&K_s[1][w * 16][0],
                16, 0, 0);
        }
        {
            const int key = lane;
            const int d0  = w * 16;
            const unsigned short* gv =
                qkv + base_v + (size_t)(jb0 + key) * rowstride + d0;
            ushort8 va = *(const ushort8*)(gv);
            ushort8 vb = *(const ushort8*)(gv + 8);
#pragma unroll
            for (int ii = 0; ii < 8; ++ii) V_s[d0 + ii][key] = va[ii];
#pragma unroll
            for (int ii = 0; ii < 8; ++ii) V_s[d0 + 8 + ii][key] = vb[ii];
        }
        __syncthreads();

        floatx4 S[4];
#pragma unroll
        for (int jb = 0; jb < 4; ++jb) {
            S[jb] = (floatx4){0.f, 0.f, 0.f, 0.f};
            bf16x8 bk0 = *(const bf16x8*)&K_s[0][jb * 16 + c15][quad * 8];
            bf16x8 bk1 = *(const bf16x8*)&K_s[1][jb * 16 + c15][quad * 8];
            S[jb] = __builtin_amdgcn_mfma_f32_16x16x32_bf16(aq[0], bk0, S[jb], 0, 0, 0);
            S[jb] = __builtin_amdgcn_mfma_f32_16x16x32_bf16(aq[1], bk1, S[jb], 0, 0, 0);
        }

        const int i_base = q0 + w * 16 + quad * 4;
        float sv[4][4];
        float mc[4] = {-1e30f, -1e30f, -1e30f, -1e30f};
#pragma unroll
        for (int jb = 0; jb < 4; ++jb) {
            const int jg = jb0 + jb * 16 + c15;
#pragma unroll
            for (int r = 0; r < 4; ++r) {
                const int rel = (i_base + r) - jg;
                float s;
                if (rel >= 0 && rel < MAXLEN) s = S[jb][r] * 0.125f + rel_s[rel];
                else                          s = -1e30f;
                sv[jb][r] = s;
                mc[r] = fmaxf(mc[r], s);
            }
        }
#pragma unroll
        for (int off = 1; off < 16; off <<= 1)
#pragma unroll
            for (int r = 0; r < 4; ++r) mc[r] = fmaxf(mc[r], __shfl_xor(mc[r], off));

        float alpha[4], psum[4];
#pragma unroll
        for (int r = 0; r < 4; ++r) {
            const float mn = fmaxf(m_r[r], mc[r]);
            alpha[r] = __expf(m_r[r] - mn);
            m_r[r] = mn;
            psum[r] = 0.f;
        }
#pragma unroll
        for (int jb = 0; jb < 4; ++jb)
#pragma unroll
            for (int r = 0; r < 4; ++r) {
                const float p = __expf(sv[jb][r] - m_r[r]);
                sv[jb][r] = p;
                psum[r] += p;
            }
#pragma unroll
        for (int off = 1; off < 16; off <<= 1)
#pragma unroll
            for (int r = 0; r < 4; ++r) psum[r] += __shfl_xor(psum[r], off);
#pragma unroll
        for (int r = 0; r < 4; ++r) l_r[r] = l_r[r] * alpha[r] + psum[r];
#pragma unroll
        for (int jb = 0; jb < 4; ++jb)
#pragma unroll
            for (int r = 0; r < 4; ++r) Oacc[jb][r] *= alpha[r];

#pragma unroll
        for (int jb = 0; jb < 4; ++jb)
#pragma unroll
            for (int r = 0; r < 4; ++r)
                P_s[w][jb >> 1][quad * 4 + r][(jb & 1) * 16 + c15] = f2bf(sv[jb][r]);

        bf16x8 ap0 = *(const bf16x8*)&P_s[w][0][c15][quad * 8];
        bf16x8 ap1 = *(const bf16x8*)&P_s[w][1][c15][quad * 8];

#pragma unroll
        for (int jd = 0; jd < 4; ++jd) {
            bf16x8 bv0 = *(const bf16x8*)&V_s[jd * 16 + c15][quad * 8];
            bf16x8 bv1 = *(const bf16x8*)&V_s[jd * 16 + c15][32 + quad * 8];
            Oacc[jd] = __builtin_amdgcn_mfma_f32_16x16x32_bf16(ap0, bv0, Oacc[jd], 0, 0, 0);
            Oacc[jd] = __builtin_amdgcn_mfma_f32_16x16x32_bf16(ap1, bv1, Oacc[jd], 0, 0, 0);
        }
    }

    float inv[4];
#pragma unroll
    for (int r = 0; r < 4; ++r) inv[r] = 1.0f / l_r[r];
#pragma unroll
    for (int jd = 0; jd < 4; ++jd) {
#pragma unroll
        for (int r = 0; r < 4; ++r) {
            const int row = q0 + w * 16 + quad * 4 + r;
            const int col = h * DD + jd * 16 + c15;
            o[(size_t)(b * NN + row) * EE + col] = f2bf(Oacc[jd][r] * inv[r]);
        }
    }
}

// ---------------------------------------------------------------------------
// Launch
// ---------------------------------------------------------------------------
extern "C" void kernel_launch(void* const* d_in, const int* in_sizes, int n_in,
                              void* d_out, int out_size, void* d_ws, size_t ws_size,
                              hipStream_t stream) {
    const float* x         = (const float*)d_in[0];
    const float* rel_pos   = (const float*)d_in[1];
    const float* in_proj_w = (const float*)d_in[2];
    const float* in_proj_b = (const float*)d_in[3];
    const float* out_w     = (const float*)d_in[4];
    const float* out_b     = (const float*)d_in[5];
    const float* w1        = (const float*)d_in[6];
    const float* b1        = (const float*)d_in[7];
    const float* w2        = (const float*)d_in[8];
    const float* b2        = (const float*)d_in[9];
    const float* ln1_g     = (const float*)d_in[10];
    const float* ln1_b     = (const float*)d_in[11];
    const float* ln2_g     = (const float*)d_in[12];
    const float* ln2_b     = (const float*)d_in[13];
    float* out = (float*)d_out;

    char* wsb = (char*)d_ws;
    const size_t MB = 1024 * 1024;
    unsigned short* wqkv_b = (unsigned short*)(wsb + 0);        // 6 MB
    unsigned short* wout_b = (unsigned short*)(wsb + 6 * MB);   // 2 MB
    unsigned short* w1_b   = (unsigned short*)(wsb + 8 * MB);   // 8 MB
    unsigned short* w2_b   = (unsigned short*)(wsb + 16 * MB);  // 8 MB
    unsigned short* xn_b   = (unsigned short*)(wsb + 24 * MB);  // 8 MB (xn, then xm)
    unsigned short* qkv_b  = (unsigned short*)(wsb + 32 * MB);  // 24 MB
    unsigned short* h_b    = (unsigned short*)(wsb + 32 * MB);  // 32 MB (reuses qkv+o)
    unsigned short* o_b    = (unsigned short*)(wsb + 56 * MB);  // 8 MB

    const int Mrows = BB * NN;   // 4096

    f2bf_kernel<<<(3 * EE * EE / 4 + 255) / 256, 256, 0, stream>>>(in_proj_w, wqkv_b, 3 * EE * EE / 4);
    f2bf_kernel<<<(EE * EE / 4 + 255) / 256, 256, 0, stream>>>(out_w, wout_b, EE * EE / 4);
    f2bf_kernel<<<(4 * EE * EE / 4 + 255) / 256, 256, 0, stream>>>(w1, w1_b, 4 * EE * EE / 4);
    f2bf_kernel<<<(4 * EE * EE / 4 + 255) / 256, 256, 0, stream>>>(w2, w2_b, 4 * EE * EE / 4);

    ln_kernel<<<Mrows, 256, 0, stream>>>(x, ln1_g, ln1_b, xn_b);
    // QKV: 256x256 pipelined kernel, grid 12x16 = 192 blocks
    gemm256_kernel<0><<<dim3(3 * EE / 256, Mrows / 256), 512, 0, stream>>>(
        xn_b, wqkv_b, in_proj_b, qkv_b, 3 * EE, EE, EE);
    attn_mfma_kernel<<<dim3(NN / 64, HH, BB), 256, 0, stream>>>(qkv_b, rel_pos, o_b);
    // out-proj + residual (old kernel): N=1024, TN=64, BK=128
    gemm_bf16_kernel<64, 4, false, true, false><<<dim3(EE / 64, Mrows / 128), 256, 0, stream>>>(
        o_b, wout_b, out_b, x, out, Mrows, EE, EE);
    ln_kernel<<<Mrows, 256, 0, stream>>>(out, ln2_g, ln2_b, xn_b);
    // FFN1: 256x256 pipelined, grid 16x16 = 256 blocks (1/CU), relu
    gemm256_kernel<1><<<dim3(4 * EE / 256, Mrows / 256), 512, 0, stream>>>(
        xn_b, w1_b, b1, h_b, 4 * EE, EE, EE);
    // FFN2: split-K=4, atomic f32 accumulate onto out (out already = x_mid);
    // bias b2 added by kz==0 blocks. grid 4x16x4 = 256 blocks, Kslice=1024.
    gemm256_kernel<2><<<dim3(EE / 256, Mrows / 256, 4), 512, 0, stream>>>(
        h_b, w2_b, b2, out, EE, 4 * EE, EE);
}

// Round 3
// 350.792 us; speedup vs baseline: 1.1002x; 1.1002x over previous
//
#include <hip/hip_runtime.h>
#include <math.h>

// Problem constants (from reference)
#define BB 4
#define NN 1024
#define EE 1024
#define HH 16
#define DD 64
#define MAXLEN 512
#define EPS 1e-5f

typedef __attribute__((ext_vector_type(8))) __bf16 bf16x8;
typedef __attribute__((ext_vector_type(4))) float floatx4;
typedef __attribute__((ext_vector_type(8))) unsigned short ushort8;

#define SWAIT(s) asm volatile("s_waitcnt " s ::: "memory")
#define SCHEDBAR() __builtin_amdgcn_sched_barrier(0)

__device__ __forceinline__ unsigned short f2bf(float f) {
    unsigned u = __float_as_uint(f);
    u += 0x7fffu + ((u >> 16) & 1u);   // RNE
    return (unsigned short)(u >> 16);
}

// ---------------------------------------------------------------------------
// fp32 -> bf16 conversion (vectorized by 4)
// ---------------------------------------------------------------------------
__global__ __launch_bounds__(256) void f2bf_kernel(const float* __restrict__ in,
                                                   unsigned short* __restrict__ out,
                                                   int n4) {
    int i = blockIdx.x * 256 + threadIdx.x;
    if (i < n4) {
        float4 v = ((const float4*)in)[i];
        ushort4 o;
        o.x = f2bf(v.x); o.y = f2bf(v.y); o.z = f2bf(v.z); o.w = f2bf(v.w);
        ((ushort4*)out)[i] = o;
    }
}

// ---------------------------------------------------------------------------
// LayerNorm: one block (256 threads) per row of E=1024; bf16 output.
// ---------------------------------------------------------------------------
__global__ __launch_bounds__(256) void ln_kernel(const float* __restrict__ x,
                                                 const float* __restrict__ g,
                                                 const float* __restrict__ b,
                                                 unsigned short* __restrict__ out) {
    const int row = blockIdx.x;
    const float* xr = x + (size_t)row * EE;
    float s = 0.f, s2 = 0.f;
    for (int j = threadIdx.x; j < EE; j += 256) {
        float v = xr[j];
        s += v; s2 += v * v;
    }
    for (int off = 32; off > 0; off >>= 1) {
        s  += __shfl_xor(s, off);
        s2 += __shfl_xor(s2, off);
    }
    __shared__ float red[8];
    const int wave = threadIdx.x >> 6, lane = threadIdx.x & 63;
    if (lane == 0) { red[wave] = s; red[4 + wave] = s2; }
    __syncthreads();
    s  = red[0] + red[1] + red[2] + red[3];
    s2 = red[4] + red[5] + red[6] + red[7];
    const float mu  = s * (1.0f / EE);
    const float var = s2 * (1.0f / EE) - mu * mu;
    const float inv = rsqrtf(var + EPS);
    unsigned short* orow = out + (size_t)row * EE;
    for (int j = threadIdx.x; j < EE; j += 256) {
        orow[j] = f2bf((xr[j] - mu) * inv * g[j] + b[j]);
    }
}

// ---------------------------------------------------------------------------
// Pipelined bf16 MFMA GEMM: C[M,Nc] = A[M,K] @ W[Nc,K]^T + bias (+res)
// Ring-4 LDS buffers (BK=32), ONE barrier per K-tile, register prefetch of
// next tile's A-frags overlapping current tile's MFMA (counted lgkmcnt),
// counted vmcnt keeps 2 tiles' staging in flight across barriers.
//
// Per K-tile t:
//   vmcnt(4)           -> tile t+1's 4 stage-loads done (t+2's in flight)
//   s_barrier          -> publish t+1 residency; seal WAR on buf[(t-1)&3]
//   stage(t+3)         -> 4 global_load_lds into buf[(t+3)&3] == buf[(t-1)&3]
//   issue bf[0..3](t), af(t+1)[0..MR)   (FIFO: queue = [af(t)][bf01][bf23][afN])
//   lgkmcnt(MR+2)      -> af(t)+bf01 ready; bf23+afN outstanding
//   MFMA cols 0,1      (LDS drains bf23+afN under this)
//   lgkmcnt(MR)        -> bf23 ready; afN outstanding into next iter
//   MFMA cols 2,3
//
// LDS swizzle (both-sides, rule #21): physical 16B slot p of row r holds
// logical quad q = p ^ ((r&15)>>1 & 3). Staging pre-swizzles the GLOBAL
// source column; reads apply the same XOR -> 2-way max bank aliasing (free).
//
// VARIANT: 0 = bias + bf16 out; 1 = bias + relu + bf16 out;
//          2 = f32 out = acc + bias + res   (res may alias Cout elementwise)
// Requires M%BM==0, Nc%BN==0, K%64==0, K/32 >= 4.
// ---------------------------------------------------------------------------
template <int BM, int BN, int WMG, int WNG, int VARIANT>
__global__ __launch_bounds__(WMG * WNG * 64, 2) void gemm_pl_kernel(
    const unsigned short* __restrict__ A,
    const unsigned short* __restrict__ W,
    const float* __restrict__ bias,
    const float* res, void* Cout, int Nc, int K) {
    constexpr int NW  = WMG * WNG;
    constexpr int WTM = BM / WMG;     // wave tile M: 128 or 64
    constexpr int WTN = BN / WNG;     // wave tile N: 64
    constexpr int MR  = WTM / 16;     // 8 or 4
    constexpr int NR  = WTN / 16;     // 4
    static_assert(NR == 4, "NR must be 4");
    constexpr int SA = BM / (16 * NW);  // A stage-writes per wave = 2
    constexpr int SB = BN / (16 * NW);  // B stage-writes per wave = 2
    static_assert(SA == 2 && SB == 2, "stage count must be 2+2");

    __shared__ unsigned short smem[4][(BM + BN) * 32];

    const int tid  = threadIdx.x;
    const int lane = tid & 63;
    const int wv   = tid >> 6;
    const int wm   = wv / WNG;
    const int wn   = wv % WNG;
    const int row0 = blockIdx.y * BM;
    const int col0 = blockIdx.x * BN;
    const int NT   = K >> 5;

    // staging: lane covers LDS row (lane>>2), slot (lane&3); source column is
    // inverse-swizzled so reads can XOR with the same pattern.
    const int srow = lane >> 2;
    const int sq   = ((lane & 3) ^ ((lane >> 3) & 3)) * 8;   // elems
    const unsigned short* Ag = A + (size_t)(row0 + srow) * K + sq;
    const unsigned short* Wg = W + (size_t)(col0 + srow) * K + sq;

    auto stage = [&](int t) {
        unsigned short* dst = &smem[t & 3][0];
#pragma unroll
        for (int s = 0; s < SA; ++s) {
            const int r = (wv + s * NW) * 16;
            __builtin_amdgcn_global_load_lds(
                (const __attribute__((address_space(1))) unsigned int*)(Ag + (size_t)r * K + t * 32),
                (__attribute__((address_space(3))) unsigned int*)(dst + r * 32), 16, 0, 0);
        }
#pragma unroll
        for (int s = 0; s < SB; ++s) {
            const int r = (wv + s * NW) * 16;
            __builtin_amdgcn_global_load_lds(
                (const __attribute__((address_space(1))) unsigned int*)(Wg + (size_t)r * K + t * 32),
                (__attribute__((address_space(3))) unsigned int*)(dst + (BM + r) * 32), 16, 0, 0);
        }
    };

    // fragment read addressing (swizzled)
    const int frow = lane & 15;
    const int quad = lane >> 4;
    const int rq   = (quad ^ ((frow >> 1) & 3)) * 8;          // elems
    const int abase = (wm * WTM + frow) * 32 + rq;
    const int bbase = (BM + wn * WTN + frow) * 32 + rq;

    floatx4 acc[MR][4];
#pragma unroll
    for (int m = 0; m < MR; ++m)
#pragma unroll
        for (int n = 0; n < 4; ++n) acc[m][n] = (floatx4){0.f, 0.f, 0.f, 0.f};

    bf16x8 afA[MR], afB[MR];

    // ---- prologue: stage tiles 0,1,2; publish tile 0; preload af(0) ----
    stage(0); stage(1); stage(2);
    SWAIT("vmcnt(8)");
    __builtin_amdgcn_s_barrier();
    SCHEDBAR();
#pragma unroll
    for (int m = 0; m < MR; ++m)
        afA[m] = *(const bf16x8*)(&smem[0][0] + abase + m * (16 * 32));

#define GEMM_BODY(T, AFC, AFN, TAIL)                                           \
    {                                                                          \
        const int t_ = (T);                                                    \
        if (!(TAIL)) {                                                         \
            if (t_ == NT - 2) SWAIT("vmcnt(0)"); else SWAIT("vmcnt(4)");       \
        }                                                                      \
        __builtin_amdgcn_s_barrier();                                          \
        SCHEDBAR();                                                            \
        if (t_ + 3 < NT) stage(t_ + 3);                                        \
        const unsigned short* buf_ = &smem[t_ & 3][0];                         \
        bf16x8 bfr0 = *(const bf16x8*)(buf_ + bbase);                          \
        bf16x8 bfr1 = *(const bf16x8*)(buf_ + bbase + 16 * 32);                \
        SCHEDBAR();                                                            \
        bf16x8 bfr2 = *(const bf16x8*)(buf_ + bbase + 32 * 32);                \
        bf16x8 bfr3 = *(const bf16x8*)(buf_ + bbase + 48 * 32);                \
        if (!(TAIL)) {                                                         \
            const unsigned short* nbuf_ = &smem[(t_ + 1) & 3][0];              \
            _Pragma("unroll")                                                  \
            for (int m = 0; m < MR; ++m)                                       \
                AFN[m] = *(const bf16x8*)(nbuf_ + abase + m * (16 * 32));      \
        }                                                                      \
        SCHEDBAR();                                                            \
        if (TAIL) { SWAIT("lgkmcnt(2)"); }                                     \
        else { if constexpr (MR == 8) SWAIT("lgkmcnt(10)");                    \
               else SWAIT("lgkmcnt(6)"); }                                     \
        SCHEDBAR();                                                            \
        __builtin_amdgcn_s_setprio(1);                                         \
        _Pragma("unroll")                                                      \
        for (int m = 0; m < MR; ++m) {                                         \
            acc[m][0] = __builtin_amdgcn_mfma_f32_16x16x32_bf16(               \
                AFC[m], bfr0, acc[m][0], 0, 0, 0);                             \
            acc[m][1] = __builtin_amdgcn_mfma_f32_16x16x32_bf16(               \
                AFC[m], bfr1, acc[m][1], 0, 0, 0);                             \
        }                                                                      \
        SCHEDBAR();                                                            \
        if (TAIL) { SWAIT("lgkmcnt(0)"); }                                     \
        else { if constexpr (MR == 8) SWAIT("lgkmcnt(8)");                     \
               else SWAIT("lgkmcnt(4)"); }                                     \
        SCHEDBAR();                                                            \
        _Pragma("unroll")                                                      \
        for (int m = 0; m < MR; ++m) {                                         \
            acc[m][2] = __builtin_amdgcn_mfma_f32_16x16x32_bf16(               \
                AFC[m], bfr2, acc[m][2], 0, 0, 0);                             \
            acc[m][3] = __builtin_amdgcn_mfma_f32_16x16x32_bf16(               \
                AFC[m], bfr3, acc[m][3], 0, 0, 0);                             \
        }                                                                      \
        __builtin_amdgcn_s_setprio(0);                                         \
        SCHEDBAR();                                                            \
    }

    // NT is even (K%64==0): 2x-unrolled loop keeps af indexing static.
    int t = 0;
    for (; t < NT - 2; t += 2) {
        GEMM_BODY(t,     afA, afB, false);
        GEMM_BODY(t + 1, afB, afA, false);
    }
    GEMM_BODY(NT - 2, afA, afB, false);
    GEMM_BODY(NT - 1, afB, afA, true);
#undef GEMM_BODY

    // ---- epilogue ----
    const int crow = (lane >> 4) * 4;
    const int ccol = lane & 15;
#pragma unroll
    for (int n = 0; n < 4; ++n) {
        const int nn = col0 + wn * WTN + n * 16 + ccol;
        const float bv = bias[nn];
#pragma unroll
        for (int m = 0; m < MR; ++m) {
#pragma unroll
            for (int r = 0; r < 4; ++r) {
                const int mm = row0 + wm * WTM + m * 16 + crow + r;
                float v = acc[m][n][r] + bv;
                if (VARIANT == 1) v = fmaxf(v, 0.f);
                if (VARIANT == 2) {
                    ((float*)Cout)[(size_t)mm * Nc + nn] = v + res[(size_t)mm * Nc + nn];
                } else {
                    ((unsigned short*)Cout)[(size_t)mm * Nc + nn] = f2bf(v);
                }
            }
        }
    }
}

// ---------------------------------------------------------------------------
// Flash-style MFMA attention. rel_bias(i,j) finite only for 0 <= i-j < 512
// (causal sliding window). One block = 64 Q rows for (b,h); 4 waves, each
// owns 16 Q rows. QK^T and PV via mfma_f32_16x16x32_bf16; online softmax.
// ---------------------------------------------------------------------------
__global__ __launch_bounds__(256) void attn_mfma_kernel(
    const unsigned short* __restrict__ qkv,
    const float* __restrict__ rel_pos,
    unsigned short* __restrict__ o) {
    __shared__ unsigned short K_s[2][64][32];     // 8 KB
    __shared__ unsigned short V_s[64][72];        // 9 KB  [d][key]
    __shared__ unsigned short P_s[4][2][16][32];  // 8 KB  per-wave
    __shared__ float rel_s[MAXLEN];               // 2 KB

    const int qt = blockIdx.x, h = blockIdx.y, b = blockIdx.z;
    const int q0 = qt * 64;
    const int tid  = threadIdx.x;
    const int lane = tid & 63;
    const int w    = tid >> 6;
    const int quad = lane >> 4;
    const int c15  = lane & 15;

    rel_s[tid]       = rel_pos[h * MAXLEN + tid];
    rel_s[tid + 256] = rel_pos[h * MAXLEN + tid + 256];

    const size_t rowstride = 3 * EE;
    const size_t base_q = (size_t)(b * NN) * rowstride + h * DD;
    const size_t base_k = base_q + EE;
    const size_t base_v = base_q + 2 * EE;

    bf16x8 aq[2];
    {
        const unsigned short* qrow =
            qkv + base_q + (size_t)(q0 + w * 16 + c15) * rowstride + quad * 8;
        aq[0] = *(const bf16x8*)(qrow);
        aq[1] = *(const bf16x8*)(qrow + 32);
    }

    floatx4 Oacc[4];
#pragma unroll
    for (int j = 0; j < 4; ++j) Oacc[j] = (floatx4){0.f, 0.f, 0.f, 0.f};
    float m_r[4], l_r[4];
#pragma unroll
    for (int r = 0; r < 4; ++r) { m_r[r] = -1e30f; l_r[r] = 0.f; }

    const int jlo = max(0, q0 - (MAXLEN - 1));
    const int c0 = jlo >> 6;
    const int c1 = (q0 + 63) >> 6;

    for (int cc = c0; cc <= c1; ++cc) {
        const int jb0 = cc << 6;
        __syncthreads();

        {
            const int krow = w * 16 + (lane >> 2);
            const int dofs = (lane & 3) * 8;
            const unsigned short* gk =
                qkv + base_k + (size_t)(jb0 + krow) * rowstride + dofs;
            __builtin_amdgcn_global_load_lds(
                (const __attribute__((address_space(1))) unsigned int*)gk,
                (__attribute__((address_space(3))) unsigned int*)&K_s[0][w * 16][0],
                16, 0, 0);
            __builtin_amdgcn_global_load_lds(
                (const __attribute__((address_space(1))) unsigned int*)(gk + 32),
                (__attribute__((address_space(3))) unsigned int*)&K_s[1][w * 16][0],
                16, 0, 0);
        }
        {
            const int key = lane;
            const int d0  = w * 16;
            const unsigned short* gv =
                qkv + base_v + (size_t)(jb0 + key) * rowstride + d0;
            ushort8 va = *(const ushort8*)(gv);
            ushort8 vb = *(const ushort8*)(gv + 8);
#pragma unroll
            for (int ii = 0; ii < 8; ++ii) V_s[d0 + ii][key] = va[ii];
#pragma unroll
            for (int ii = 0; ii < 8; ++ii) V_s[d0 + 8 + ii][key] = vb[ii];
        }
        __syncthreads();

        floatx4 S[4];
#pragma unroll
        for (int jb = 0; jb < 4; ++jb) {
            S[jb] = (floatx4){0.f, 0.f, 0.f, 0.f};
            bf16x8 bk0 = *(const bf16x8*)&K_s[0][jb * 16 + c15][quad * 8];
            bf16x8 bk1 = *(const bf16x8*)&K_s[1][jb * 16 + c15][quad * 8];
            S[jb] = __builtin_amdgcn_mfma_f32_16x16x32_bf16(aq[0], bk0, S[jb], 0, 0, 0);
            S[jb] = __builtin_amdgcn_mfma_f32_16x16x32_bf16(aq[1], bk1, S[jb], 0, 0, 0);
        }

        const int i_base = q0 + w * 16 + quad * 4;
        float sv[4][4];
        float mc[4] = {-1e30f, -1e30f, -1e30f, -1e30f};
#pragma unroll
        for (int jb = 0; jb < 4; ++jb) {
            const int jg = jb0 + jb * 16 + c15;
#pragma unroll
            for (int r = 0; r < 4; ++r) {
                const int rel = (i_base + r) - jg;
                float s;
                if (rel >= 0 && rel < MAXLEN) s = S[jb][r] * 0.125f + rel_s[rel];
                else                          s = -1e30f;
                sv[jb][r] = s;
                mc[r] = fmaxf(mc[r], s);
            }
        }
#pragma unroll
        for (int off = 1; off < 16; off <<= 1)
#pragma unroll
            for (int r = 0; r < 4; ++r) mc[r] = fmaxf(mc[r], __shfl_xor(mc[r], off));

        float alpha[4], psum[4];
#pragma unroll
        for (int r = 0; r < 4; ++r) {
            const float mn = fmaxf(m_r[r], mc[r]);
            alpha[r] = __expf(m_r[r] - mn);
            m_r[r] = mn;
            psum[r] = 0.f;
        }
#pragma unroll
        for (int jb = 0; jb < 4; ++jb)
#pragma unroll
            for (int r = 0; r < 4; ++r) {
                const float p = __expf(sv[jb][r] - m_r[r]);
                sv[jb][r] = p;
                psum[r] += p;
            }
#pragma unroll
        for (int off = 1; off < 16; off <<= 1)
#pragma unroll
            for (int r = 0; r < 4; ++r) psum[r] += __shfl_xor(psum[r], off);
#pragma unroll
        for (int r = 0; r < 4; ++r) l_r[r] = l_r[r] * alpha[r] + psum[r];
#pragma unroll
        for (int jb = 0; jb < 4; ++jb)
#pragma unroll
            for (int r = 0; r < 4; ++r) Oacc[jb][r] *= alpha[r];

#pragma unroll
        for (int jb = 0; jb < 4; ++jb)
#pragma unroll
            for (int r = 0; r < 4; ++r)
                P_s[w][jb >> 1][quad * 4 + r][(jb & 1) * 16 + c15] = f2bf(sv[jb][r]);

        bf16x8 ap0 = *(const bf16x8*)&P_s[w][0][c15][quad * 8];
        bf16x8 ap1 = *(const bf16x8*)&P_s[w][1][c15][quad * 8];

#pragma unroll
        for (int jd = 0; jd < 4; ++jd) {
            bf16x8 bv0 = *(const bf16x8*)&V_s[jd * 16 + c15][quad * 8];
            bf16x8 bv1 = *(const bf16x8*)&V_s[jd * 16 + c15][32 + quad * 8];
            Oacc[jd] = __builtin_amdgcn_mfma_f32_16x16x32_bf16(ap0, bv0, Oacc[jd], 0, 0, 0);
            Oacc[jd] = __builtin_amdgcn_mfma_f32_16x16x32_bf16(ap1, bv1, Oacc[jd], 0, 0, 0);
        }
    }

    float inv[4];
#pragma unroll
    for (int r = 0; r < 4; ++r) inv[r] = 1.0f / l_r[r];
#pragma unroll
    for (int jd = 0; jd < 4; ++jd) {
#pragma unroll
        for (int r = 0; r < 4; ++r) {
            const int row = q0 + w * 16 + quad * 4 + r;
            const int col = h * DD + jd * 16 + c15;
            o[(size_t)(b * NN + row) * EE + col] = f2bf(Oacc[jd][r] * inv[r]);
        }
    }
}

// ---------------------------------------------------------------------------
// Launch
// ---------------------------------------------------------------------------
extern "C" void kernel_launch(void* const* d_in, const int* in_sizes, int n_in,
                              void* d_out, int out_size, void* d_ws, size_t ws_size,
                              hipStream_t stream) {
    const float* x         = (const float*)d_in[0];
    const float* rel_pos   = (const float*)d_in[1];
    const float* in_proj_w = (const float*)d_in[2];
    const float* in_proj_b = (const float*)d_in[3];
    const float* out_w     = (const float*)d_in[4];
    const float* out_b     = (const float*)d_in[5];
    const float* w1        = (const float*)d_in[6];
    const float* b1        = (const float*)d_in[7];
    const float* w2        = (const float*)d_in[8];
    const float* b2        = (const float*)d_in[9];
    const float* ln1_g     = (const float*)d_in[10];
    const float* ln1_b     = (const float*)d_in[11];
    const float* ln2_g     = (const float*)d_in[12];
    const float* ln2_b     = (const float*)d_in[13];
    float* out = (float*)d_out;

    char* wsb = (char*)d_ws;
    const size_t MB = 1024 * 1024;
    unsigned short* wqkv_b = (unsigned short*)(wsb + 0);        // 6 MB
    unsigned short* wout_b = (unsigned short*)(wsb + 6 * MB);   // 2 MB
    unsigned short* w1_b   = (unsigned short*)(wsb + 8 * MB);   // 8 MB
    unsigned short* w2_b   = (unsigned short*)(wsb + 16 * MB);  // 8 MB
    unsigned short* xn_b   = (unsigned short*)(wsb + 24 * MB);  // 8 MB (xn, then xm)
    unsigned short* qkv_b  = (unsigned short*)(wsb + 32 * MB);  // 24 MB
    unsigned short* h_b    = (unsigned short*)(wsb + 32 * MB);  // 32 MB (reuses qkv+o)
    unsigned short* o_b    = (unsigned short*)(wsb + 56 * MB);  // 8 MB

    const int Mrows = BB * NN;   // 4096

    f2bf_kernel<<<(3 * EE * EE / 4 + 255) / 256, 256, 0, stream>>>(in_proj_w, wqkv_b, 3 * EE * EE / 4);
    f2bf_kernel<<<(EE * EE / 4 + 255) / 256, 256, 0, stream>>>(out_w, wout_b, EE * EE / 4);
    f2bf_kernel<<<(4 * EE * EE / 4 + 255) / 256, 256, 0, stream>>>(w1, w1_b, 4 * EE * EE / 4);
    f2bf_kernel<<<(4 * EE * EE / 4 + 255) / 256, 256, 0, stream>>>(w2, w2_b, 4 * EE * EE / 4);

    ln_kernel<<<Mrows, 256, 0, stream>>>(x, ln1_g, ln1_b, xn_b);
    // QKV: 256x256 pipelined, grid 12x16 = 192 blocks
    gemm_pl_kernel<256, 256, 2, 4, 0><<<dim3(3 * EE / 256, Mrows / 256), 512, 0, stream>>>(
        xn_b, wqkv_b, in_proj_b, nullptr, qkv_b, 3 * EE, EE);
    attn_mfma_kernel<<<dim3(NN / 64, HH, BB), 256, 0, stream>>>(qkv_b, rel_pos, o_b);
    // out-proj + residual: 128x128 pipelined, grid 8x32 = 256 blocks (2/CU)
    gemm_pl_kernel<128, 128, 2, 2, 2><<<dim3(EE / 128, Mrows / 128), 256, 0, stream>>>(
        o_b, wout_b, out_b, x, out, EE, EE);
    ln_kernel<<<Mrows, 256, 0, stream>>>(out, ln2_g, ln2_b, xn_b);
    // FFN1: 256x256 pipelined, grid 16x16 = 256 blocks, relu
    gemm_pl_kernel<256, 256, 2, 4, 1><<<dim3(4 * EE / 256, Mrows / 256), 512, 0, stream>>>(
        xn_b, w1_b, b1, nullptr, h_b, 4 * EE, EE);
    // FFN2 + residual (in-place on d_out): 128x128 pipelined, grid 8x32,
    // K=4096; natural XCD mapping pins one W2 column-panel per XCD L2.
    gemm_pl_kernel<128, 128, 2, 2, 2><<<dim3(EE / 128, Mrows / 128), 256, 0, stream>>>(
        h_b, w2_b, b2, out, out, EE, 4 * EE);
}